// Round 4
// baseline (967.609 us; speedup 1.0000x reference)
//
#include <hip/hip_runtime.h>
#include <cstddef>
#include <cstdint>

#define NNODES 8192
#define BATCH  16
#define HID    64
#define NEDGE  131072
#define SN     524288   // NNODES * HID (per-batch state stride)
#define OUTHALF 8388608 // BATCH * SN
#define ROWE   384      // padded K per (n,b) row: 5 slices * 72 + 24 tail pad
#define SLICE  72       // per-matrix padded feature count (66 real + 6 pad)
#define NBROW  6144     // 16 * ROWE elems per node
#define GN     8        // nodes per GEMM block

typedef __attribute__((ext_vector_type(8))) short bf16x8;
typedef __attribute__((ext_vector_type(4))) float f32x4;

static __device__ __forceinline__ float bf2f(ushort u) {
    union { uint32_t i; float f; } c; c.i = ((uint32_t)u) << 16; return c.f;
}
static __device__ __forceinline__ ushort f2bf(float f) {
    union { float f; uint32_t i; } c; c.f = f;
    uint32_t lsb = (c.i >> 16) & 1;
    return (ushort)((c.i + 0x7fffu + lsb) >> 16);
}

// ---------------- CSR construction ----------------

__global__ void zero_counts_kernel(int* __restrict__ c1, int* __restrict__ c2) {
    int i = blockIdx.x * 256 + threadIdx.x;
    if (i < NNODES) { c1[i] = 0; c2[i] = 0; }
}

__global__ void hist_kernel(const int* __restrict__ src, const int* __restrict__ dst,
                            int* __restrict__ c1, int* __restrict__ c2) {
    int e = blockIdx.x * 256 + threadIdx.x;
    if (e < NEDGE) {
        atomicAdd(&c1[src[e]], 1);
        atomicAdd(&c2[dst[e]], 1);
    }
}

__global__ __launch_bounds__(1024) void scan_kernel(const int* __restrict__ counts,
                                                    int* __restrict__ rowptr,
                                                    int* __restrict__ cursor) {
    __shared__ int sh[1024];
    int tid = threadIdx.x;
    int base = tid * 8;
    int local[8];
    int sum = 0;
#pragma unroll
    for (int j = 0; j < 8; ++j) { local[j] = counts[base + j]; sum += local[j]; }
    sh[tid] = sum;
    __syncthreads();
    for (int off = 1; off < 1024; off <<= 1) {
        int v = (tid >= off) ? sh[tid - off] : 0;
        __syncthreads();
        sh[tid] += v;
        __syncthreads();
    }
    int p = sh[tid] - sum;
#pragma unroll
    for (int j = 0; j < 8; ++j) {
        cursor[base + j] = p;
        p += local[j];
        rowptr[base + j + 1] = p;
    }
    if (tid == 0) rowptr[0] = 0;
}

__global__ void scatter_kernel(const int* __restrict__ src, const int* __restrict__ dst,
                               const float* __restrict__ v1, const float* __restrict__ v2,
                               int* __restrict__ cur1, int* __restrict__ cur2,
                               int* __restrict__ cols1, float* __restrict__ valsC1,
                               int* __restrict__ cols2, float* __restrict__ valsC2) {
    int e = blockIdx.x * 256 + threadIdx.x;
    if (e < NEDGE) {
        int r1 = src[e];
        int p1 = atomicAdd(&cur1[r1], 1);
        cols1[p1] = dst[e];
        valsC1[p1] = v1[e];
        int r2 = dst[e];
        int p2 = atomicAdd(&cur2[r2], 1);
        cols2[p2] = src[e];
        valsC2[p2] = v2[e];
    }
}

// ------- weight transpose + bf16: W[k_ref=f*5+m][C] -> WT[col][kk=m*72+f] (pad=0) -------

__global__ void convert_w_kernel(const float* __restrict__ Wg, const float* __restrict__ Wc,
                                 ushort* __restrict__ WgT, ushort* __restrict__ WcT) {
    int i = blockIdx.x * 256 + threadIdx.x;
    if (i >= 192 * ROWE) return;
    int col = i / ROWE, kk = i - col * ROWE;
    int m = kk / SLICE, f = kk - m * SLICE;
    bool real = (m < 5) && (f < 66);
    if (col < 128) {
        WgT[col * ROWE + kk] = real ? f2bf(Wg[(f * 5 + m) * 128 + col]) : (ushort)0;
    } else {
        int c = col - 128;
        WcT[c * ROWE + kk] = real ? f2bf(Wc[(f * 5 + m) * 64 + c]) : (ushort)0;
    }
}

// ---------------- init x0: x_all[n][b][0..71] = slice0 (+pad), zero tail ----------------
// thread i -> (nb = i/12, piece p = i%12); p<9: slice0 uint4 piece; p>=9: tail zero piece

__global__ void init_x0_kernel(const float* __restrict__ inputs, const float* __restrict__ state,
                               ushort* __restrict__ x_all) {
    int i = blockIdx.x * 256 + threadIdx.x;
    if (i >= NNODES * 16 * 12) return;
    int nb = i / 12, p = i - nb * 12;
    int n = nb >> 4, b = nb & 15;
    if (p >= 9) {
        *(uint4*)(x_all + (size_t)nb * ROWE + 360 + (p - 9) * 8) = make_uint4(0, 0, 0, 0);
        return;
    }
    float v[8];
#pragma unroll
    for (int k = 0; k < 8; ++k) {
        int e = 8 * p + k;
        if (e < 2)       v[k] = inputs[b * (NNODES * 2) + n * 2 + e];
        else if (e < 66) v[k] = state[(size_t)b * SN + n * HID + (e - 2)];
        else             v[k] = 0.f;
    }
    uint4 r;
    r.x = (uint32_t)f2bf(v[0]) | ((uint32_t)f2bf(v[1]) << 16);
    r.y = (uint32_t)f2bf(v[2]) | ((uint32_t)f2bf(v[3]) << 16);
    r.z = (uint32_t)f2bf(v[4]) | ((uint32_t)f2bf(v[5]) << 16);
    r.w = (uint32_t)f2bf(v[6]) | ((uint32_t)f2bf(v[7]) << 16);
    *(uint4*)(x_all + (size_t)nb * ROWE + 8 * p) = r;
}

// ---------------- SPMM on padded slices (bf16, fp32 accumulate) ----------------
// xin/xp/yout point at x_all + sliceOffset. Per node: 144 uint4 pieces (16 b x 9).
// block = 128: thread t -> piece t; t<16 also piece 128+t.

static __device__ __forceinline__ void fma8(float* acc, uint4 d, float v) {
    acc[0] += v * bf2f((ushort)(d.x));  acc[1] += v * bf2f((ushort)(d.x >> 16));
    acc[2] += v * bf2f((ushort)(d.y));  acc[3] += v * bf2f((ushort)(d.y >> 16));
    acc[4] += v * bf2f((ushort)(d.z));  acc[5] += v * bf2f((ushort)(d.z >> 16));
    acc[6] += v * bf2f((ushort)(d.w));  acc[7] += v * bf2f((ushort)(d.w >> 16));
}

static __device__ __forceinline__ uint4 blend_pack8(const float* acc, uint4 p,
                                                    float alpha, float beta) {
    float o[8];
    o[0] = alpha * acc[0] + beta * bf2f((ushort)(p.x));
    o[1] = alpha * acc[1] + beta * bf2f((ushort)(p.x >> 16));
    o[2] = alpha * acc[2] + beta * bf2f((ushort)(p.y));
    o[3] = alpha * acc[3] + beta * bf2f((ushort)(p.y >> 16));
    o[4] = alpha * acc[4] + beta * bf2f((ushort)(p.z));
    o[5] = alpha * acc[5] + beta * bf2f((ushort)(p.z >> 16));
    o[6] = alpha * acc[6] + beta * bf2f((ushort)(p.w));
    o[7] = alpha * acc[7] + beta * bf2f((ushort)(p.w >> 16));
    uint4 r;
    r.x = (uint32_t)f2bf(o[0]) | ((uint32_t)f2bf(o[1]) << 16);
    r.y = (uint32_t)f2bf(o[2]) | ((uint32_t)f2bf(o[3]) << 16);
    r.z = (uint32_t)f2bf(o[4]) | ((uint32_t)f2bf(o[5]) << 16);
    r.w = (uint32_t)f2bf(o[6]) | ((uint32_t)f2bf(o[7]) << 16);
    return r;
}

__global__ __launch_bounds__(128) void spmm_kernel(const int* __restrict__ rowptr,
                                                   const int* __restrict__ cols,
                                                   const float* __restrict__ vals,
                                                   const ushort* __restrict__ xin,
                                                   const ushort* __restrict__ xp,
                                                   ushort* __restrict__ yout,
                                                   float alpha, float beta) {
    int n = blockIdx.x;
    int t = threadIdx.x;
    int lane = t & 63;
    int b0 = t / 9, j0 = t - b0 * 9;
    int p1 = 128 + t;
    int b1 = p1 / 9, j1 = p1 - b1 * 9;
    int off0 = b0 * ROWE + j0 * 8;
    int off1 = b1 * ROWE + j1 * 8;
    bool tail = t < 16;

    int s = rowptr[n], e = rowptr[n + 1];
    float a0[8] = {0, 0, 0, 0, 0, 0, 0, 0};
    float a1[8] = {0, 0, 0, 0, 0, 0, 0, 0};

    for (int base = s; base < e; base += 64) {
        int rem = e - base;
        if (rem > 64) rem = 64;
        int mc = 0; float mv = 0.f;
        if (lane < rem) { mc = cols[base + lane]; mv = vals[base + lane]; }
        for (int j = 0; j < rem; j += 4) {
            int   c0 = __shfl(mc, j);
            float v0 = __shfl(mv, j);
            int   c1 = __shfl(mc, (j + 1) & 63);
            float v1 = (j + 1 < rem) ? __shfl(mv, (j + 1) & 63) : 0.f;
            int   c2 = __shfl(mc, (j + 2) & 63);
            float v2 = (j + 2 < rem) ? __shfl(mv, (j + 2) & 63) : 0.f;
            int   c3 = __shfl(mc, (j + 3) & 63);
            float v3 = (j + 3 < rem) ? __shfl(mv, (j + 3) & 63) : 0.f;
            const ushort* s0 = xin + (size_t)c0 * NBROW;
            const ushort* s1 = xin + (size_t)c1 * NBROW;
            const ushort* s2 = xin + (size_t)c2 * NBROW;
            const ushort* s3 = xin + (size_t)c3 * NBROW;
            uint4 d0 = *(const uint4*)(s0 + off0);
            uint4 d1 = *(const uint4*)(s1 + off0);
            uint4 d2 = *(const uint4*)(s2 + off0);
            uint4 d3 = *(const uint4*)(s3 + off0);
            fma8(a0, d0, v0); fma8(a0, d1, v1); fma8(a0, d2, v2); fma8(a0, d3, v3);
            if (tail) {
                uint4 e0 = *(const uint4*)(s0 + off1);
                uint4 e1 = *(const uint4*)(s1 + off1);
                uint4 e2 = *(const uint4*)(s2 + off1);
                uint4 e3 = *(const uint4*)(s3 + off1);
                fma8(a1, e0, v0); fma8(a1, e1, v1); fma8(a1, e2, v2); fma8(a1, e3, v3);
            }
        }
    }
    const ushort* xpr = xp + (size_t)n * NBROW;
    ushort* yr = yout + (size_t)n * NBROW;
    uint4 pp0 = (beta != 0.f) ? *(const uint4*)(xpr + off0) : make_uint4(0, 0, 0, 0);
    *(uint4*)(yr + off0) = blend_pack8(a0, pp0, alpha, beta);
    if (tail) {
        uint4 pp1 = (beta != 0.f) ? *(const uint4*)(xpr + off1) : make_uint4(0, 0, 0, 0);
        *(uint4*)(yr + off1) = blend_pack8(a1, pp1, alpha, beta);
    }
}

// ---------------- gate GEMM (MFMA, no LDS) + sigmoid + r*state + u ----------------
// 256 thr = 4 waves; wave w: col tiles {2w,2w+1} (cols 32w..32w+31). A-frags direct from global.

__global__ __launch_bounds__(256) void gate_mfma(const ushort* __restrict__ x_all,
                                                 const ushort* __restrict__ WgT,
                                                 const float* __restrict__ bg,
                                                 const float* __restrict__ state,
                                                 float* __restrict__ U,
                                                 ushort* __restrict__ x_mut) {
    int tid = threadIdx.x;
    int wave = tid >> 6, lane = tid & 63;
    int row = lane & 15, quad = lane >> 4;
    int c0 = wave * 32 + row;
    int c1 = c0 + 16;

    bf16x8 w0[12], w1[12];
#pragma unroll
    for (int k = 0; k < 12; ++k) {
        w0[k] = *(const bf16x8*)(WgT + (size_t)c0 * ROWE + k * 32 + quad * 8);
        w1[k] = *(const bf16x8*)(WgT + (size_t)c1 * ROWE + k * 32 + quad * 8);
    }
    float bias0 = bg[c0], bias1 = bg[c1];

    int nodeBase = blockIdx.x * GN;
    for (int g = 0; g < GN; ++g) {
        int n = nodeBase + g;
        const ushort* Ab = x_all + ((size_t)n * 16 + row) * ROWE + quad * 8;
        bf16x8 a[12];
#pragma unroll
        for (int k = 0; k < 12; ++k) a[k] = *(const bf16x8*)(Ab + k * 32);

        f32x4 acc0 = {0.f, 0.f, 0.f, 0.f};
        f32x4 acc1 = {0.f, 0.f, 0.f, 0.f};
#pragma unroll
        for (int k = 0; k < 12; ++k) {
            acc0 = __builtin_amdgcn_mfma_f32_16x16x32_bf16(a[k], w0[k], acc0, 0, 0, 0);
            acc1 = __builtin_amdgcn_mfma_f32_16x16x32_bf16(a[k], w1[k], acc1, 0, 0, 0);
        }
        // D[b = quad*4+r][col = lane&15 -> c0/c1]
#pragma unroll
        for (int r = 0; r < 4; ++r) {
            int b = quad * 4 + r;
            float v0 = 1.f / (1.f + __expf(-(acc0[r] + bias0)));
            float v1 = 1.f / (1.f + __expf(-(acc1[r] + bias1)));
            if (wave < 2) {  // cols 0..63: r-gate -> slice0 state part (bf16)
                float s0 = state[(size_t)b * SN + n * HID + c0];
                float s1 = state[(size_t)b * SN + n * HID + c1];
                x_mut[((size_t)n * 16 + b) * ROWE + 2 + c0] = f2bf(v0 * s0);
                x_mut[((size_t)n * 16 + b) * ROWE + 2 + c1] = f2bf(v1 * s1);
            } else {         // cols 64..127: u-gate (fp32)
                U[(size_t)b * SN + n * HID + (c0 - HID)] = v0;
                U[(size_t)b * SN + n * HID + (c1 - HID)] = v1;
            }
        }
    }
}

// ---------------- candidate GEMM (MFMA, no LDS) + tanh + GRU update + output ----------------

__global__ __launch_bounds__(256) void cand_mfma(const ushort* __restrict__ x_all,
                                                 const ushort* __restrict__ WcT,
                                                 const float* __restrict__ bc,
                                                 const float* __restrict__ state,
                                                 const float* __restrict__ U,
                                                 float* __restrict__ out) {
    int tid = threadIdx.x;
    int wave = tid >> 6, lane = tid & 63;
    int row = lane & 15, quad = lane >> 4;
    int c = wave * 16 + row;

    bf16x8 w[12];
#pragma unroll
    for (int k = 0; k < 12; ++k)
        w[k] = *(const bf16x8*)(WcT + (size_t)c * ROWE + k * 32 + quad * 8);
    float bias = bc[c];

    int nodeBase = blockIdx.x * GN;
    for (int g = 0; g < GN; ++g) {
        int n = nodeBase + g;
        const ushort* Ab = x_all + ((size_t)n * 16 + row) * ROWE + quad * 8;
        bf16x8 a[12];
#pragma unroll
        for (int k = 0; k < 12; ++k) a[k] = *(const bf16x8*)(Ab + k * 32);

        f32x4 acc = {0.f, 0.f, 0.f, 0.f};
#pragma unroll
        for (int k = 0; k < 12; ++k)
            acc = __builtin_amdgcn_mfma_f32_16x16x32_bf16(a[k], w[k], acc, 0, 0, 0);

#pragma unroll
        for (int r = 0; r < 4; ++r) {
            int b = quad * 4 + r;
            float pre = acc[r] + bias;
            float cv = 1.f - 2.f / (__expf(2.f * pre) + 1.f);  // tanh
            size_t idx = (size_t)b * SN + n * HID + c;
            float uv = U[idx];
            float s = state[idx];
            float ns = uv * s + (1.f - uv) * cv;
            out[idx] = ns;
            out[OUTHALF + idx] = ns;
        }
    }
}

// ---------------- launch ----------------

extern "C" void kernel_launch(void* const* d_in, const int* in_sizes, int n_in,
                              void* d_out, int out_size, void* d_ws, size_t ws_size,
                              hipStream_t stream) {
    const float* inputs = (const float*)d_in[0];
    const float* state  = (const float*)d_in[1];
    const int*   esrc   = (const int*)d_in[2];
    const int*   edst   = (const int*)d_in[3];
    const float* v1     = (const float*)d_in[4];
    const float* v2     = (const float*)d_in[5];
    const float* Wg     = (const float*)d_in[6];
    const float* bg     = (const float*)d_in[7];
    const float* Wc     = (const float*)d_in[8];
    const float* bc     = (const float*)d_in[9];
    float* out = (float*)d_out;

    char* ws = (char*)d_ws;
    size_t off = 0;
    auto alloc = [&](size_t bytes) -> void* {
        void* p = ws + off;
        off += (bytes + 255) & ~(size_t)255;
        return p;
    };
    ushort* x_all  = (ushort*)alloc((size_t)NNODES * NBROW * 2);  // 100.7 MB
    float*  U      = (float*)alloc((size_t)OUTHALF * 4);          // 33.5 MB
    ushort* WgT    = (ushort*)alloc((size_t)128 * ROWE * 2);
    ushort* WcT    = (ushort*)alloc((size_t)64 * ROWE * 2);
    int*   counts1 = (int*)alloc(NNODES * 4);
    int*   counts2 = (int*)alloc(NNODES * 4);
    int*   rowptr1 = (int*)alloc((NNODES + 1) * 4);
    int*   rowptr2 = (int*)alloc((NNODES + 1) * 4);
    int*   cursor1 = (int*)alloc(NNODES * 4);
    int*   cursor2 = (int*)alloc(NNODES * 4);
    int*   cols1   = (int*)alloc(NEDGE * 4);
    int*   cols2   = (int*)alloc(NEDGE * 4);
    float* valsC1  = (float*)alloc(NEDGE * 4);
    float* valsC2  = (float*)alloc(NEDGE * 4);

    // slice base pointers (elems): slice m at offset m*72 within each (n,b) row
    ushort* S0 = x_all;
    ushort* S1 = x_all + 1 * SLICE;
    ushort* S2 = x_all + 2 * SLICE;
    ushort* S3 = x_all + 3 * SLICE;
    ushort* S4 = x_all + 4 * SLICE;

    // CSR build (graph shared by both diff_convs)
    zero_counts_kernel<<<(NNODES + 255) / 256, 256, 0, stream>>>(counts1, counts2);
    hist_kernel<<<(NEDGE + 255) / 256, 256, 0, stream>>>(esrc, edst, counts1, counts2);
    scan_kernel<<<1, 1024, 0, stream>>>(counts1, rowptr1, cursor1);
    scan_kernel<<<1, 1024, 0, stream>>>(counts2, rowptr2, cursor2);
    scatter_kernel<<<(NEDGE + 255) / 256, 256, 0, stream>>>(esrc, edst, v1, v2,
                                                            cursor1, cursor2,
                                                            cols1, valsC1, cols2, valsC2);

    convert_w_kernel<<<(192 * ROWE + 255) / 256, 256, 0, stream>>>(Wg, Wc, WgT, WcT);
    init_x0_kernel<<<(NNODES * 16 * 12 + 255) / 256, 256, 0, stream>>>(inputs, state, x_all);

    // diff_conv #1 diffusion
    spmm_kernel<<<NNODES, 128, 0, stream>>>(rowptr1, cols1, valsC1, S0, S0, S1, 1.f, 0.f);
    spmm_kernel<<<NNODES, 128, 0, stream>>>(rowptr1, cols1, valsC1, S1, S0, S2, 2.f, -1.f);
    spmm_kernel<<<NNODES, 128, 0, stream>>>(rowptr2, cols2, valsC2, S0, S0, S3, 1.f, 0.f);
    spmm_kernel<<<NNODES, 128, 0, stream>>>(rowptr2, cols2, valsC2, S3, S0, S4, 2.f, -1.f);

    // gate GEMM + sigmoid; writes U, overwrites slice0 state-part with r*state (-> xc)
    gate_mfma<<<NNODES / GN, 256, 0, stream>>>(x_all, WgT, bg, state, U, x_all);

    // diff_conv #2 diffusion on xc
    spmm_kernel<<<NNODES, 128, 0, stream>>>(rowptr1, cols1, valsC1, S0, S0, S1, 1.f, 0.f);
    spmm_kernel<<<NNODES, 128, 0, stream>>>(rowptr1, cols1, valsC1, S1, S0, S2, 2.f, -1.f);
    spmm_kernel<<<NNODES, 128, 0, stream>>>(rowptr2, cols2, valsC2, S0, S0, S3, 1.f, 0.f);
    spmm_kernel<<<NNODES, 128, 0, stream>>>(rowptr2, cols2, valsC2, S3, S0, S4, 2.f, -1.f);

    // candidate GEMM + tanh + GRU update + duplicated output
    cand_mfma<<<NNODES / GN, 256, 0, stream>>>(x_all, WcT, bc, state, U, out);
}

// Round 5
// 705.695 us; speedup vs baseline: 1.3711x; 1.3711x over previous
//
#include <hip/hip_runtime.h>
#include <cstddef>
#include <cstdint>

#define NNODES 8192
#define HID    64
#define NEDGE  131072
#define SN     524288    // NNODES * HID (per-batch stride in state/out)
#define OUTHALF 8388608  // BATCH * SN
#define CCH    1056      // 66 features * 16 batch, per node per slice
#define NFB    8650752   // NNODES * CCH
#define ROWE   384       // K-major padded row: 5*72 + 24 tail
#define SLICE  72
#define GN     4         // nodes per GEMM block

typedef __attribute__((ext_vector_type(8))) short bf16x8;
typedef __attribute__((ext_vector_type(4))) float f32x4;

static __device__ __forceinline__ float bf2f(ushort u) {
    union { uint32_t i; float f; } c; c.i = ((uint32_t)u) << 16; return c.f;
}
static __device__ __forceinline__ ushort f2bf(float f) {
    union { float f; uint32_t i; } c; c.f = f;
    uint32_t lsb = (c.i >> 16) & 1;
    return (ushort)((c.i + 0x7fffu + lsb) >> 16);
}

// ---------------- CSR construction ----------------

__global__ void zero_counts_kernel(int* __restrict__ c1, int* __restrict__ c2) {
    int i = blockIdx.x * 256 + threadIdx.x;
    if (i < NNODES) { c1[i] = 0; c2[i] = 0; }
}

__global__ void hist_kernel(const int* __restrict__ src, const int* __restrict__ dst,
                            int* __restrict__ c1, int* __restrict__ c2) {
    int e = blockIdx.x * 256 + threadIdx.x;
    if (e < NEDGE) {
        atomicAdd(&c1[src[e]], 1);
        atomicAdd(&c2[dst[e]], 1);
    }
}

__global__ __launch_bounds__(1024) void scan_kernel(const int* __restrict__ counts,
                                                    int* __restrict__ rowptr,
                                                    int* __restrict__ cursor) {
    __shared__ int sh[1024];
    int tid = threadIdx.x;
    int base = tid * 8;
    int local[8];
    int sum = 0;
#pragma unroll
    for (int j = 0; j < 8; ++j) { local[j] = counts[base + j]; sum += local[j]; }
    sh[tid] = sum;
    __syncthreads();
    for (int off = 1; off < 1024; off <<= 1) {
        int v = (tid >= off) ? sh[tid - off] : 0;
        __syncthreads();
        sh[tid] += v;
        __syncthreads();
    }
    int p = sh[tid] - sum;
#pragma unroll
    for (int j = 0; j < 8; ++j) {
        cursor[base + j] = p;
        p += local[j];
        rowptr[base + j + 1] = p;
    }
    if (tid == 0) rowptr[0] = 0;
}

__global__ void scatter_kernel(const int* __restrict__ src, const int* __restrict__ dst,
                               const float* __restrict__ v1, const float* __restrict__ v2,
                               int* __restrict__ cur1, int* __restrict__ cur2,
                               int* __restrict__ cols1, float* __restrict__ valsC1,
                               int* __restrict__ cols2, float* __restrict__ valsC2) {
    int e = blockIdx.x * 256 + threadIdx.x;
    if (e < NEDGE) {
        int r1 = src[e];
        int p1 = atomicAdd(&cur1[r1], 1);
        cols1[p1] = dst[e];
        valsC1[p1] = v1[e];
        int r2 = dst[e];
        int p2 = atomicAdd(&cur2[r2], 1);
        cols2[p2] = src[e];
        valsC2[p2] = v2[e];
    }
}

// ------- weight: W[k_ref=f*5+m][C] -> WT[col][kk=m*72+f] bf16, pads (f>=66, kk>=360) zero -------

__global__ void convert_w_kernel(const float* __restrict__ Wg, const float* __restrict__ Wc,
                                 ushort* __restrict__ WgT, ushort* __restrict__ WcT) {
    int i = blockIdx.x * 256 + threadIdx.x;
    if (i >= 192 * ROWE) return;
    int col = i / ROWE, kk = i - col * ROWE;
    int m = kk / SLICE, f = kk - m * SLICE;
    bool real = (m < 5) && (f < 66);
    if (col < 128) {
        WgT[col * ROWE + kk] = real ? f2bf(Wg[(f * 5 + m) * 128 + col]) : (ushort)0;
    } else {
        int c = col - 128;
        WcT[c * ROWE + kk] = real ? f2bf(Wc[(f * 5 + m) * 64 + c]) : (ushort)0;
    }
}

// ---------------- st[row=(n,b)][c] = bf16(state[b][n][c]) ----------------

__global__ void st_build_kernel(const float* __restrict__ state, ushort* __restrict__ st) {
    int i = blockIdx.x * 256 + threadIdx.x;
    if (i >= (SN * 16) / 4) return;
    size_t idx4 = (size_t)i * 4;
    int b = (int)(idx4 >> 19);          // SN = 2^19
    int r = (int)(idx4 & (SN - 1));
    int n = r >> 6, c = r & 63;
    float4 v = *(const float4*)(state + idx4);
    uint2 o;
    o.x = (uint32_t)f2bf(v.x) | ((uint32_t)f2bf(v.y) << 16);
    o.y = (uint32_t)f2bf(v.z) | ((uint32_t)f2bf(v.w) << 16);
    *(uint2*)(st + ((size_t)((n << 4) + b)) * 64 + c) = o;
}

// ------- init x0: slice0 [n][f][b] contiguous + dual-write K-major x_all[row][f] -------

__global__ void init_x0_kernel(const float* __restrict__ inputs, const float* __restrict__ state,
                               ushort* __restrict__ Xs0, ushort* __restrict__ x_all) {
    int i = blockIdx.x * 256 + threadIdx.x;
    if (i >= NFB / 8) return;
    int n = i / 132, rc = i - n * 132;
    int f = rc >> 1, b0 = (rc & 1) * 8;
    float v[8];
#pragma unroll
    for (int j = 0; j < 8; ++j) {
        int b = b0 + j;
        v[j] = (f < 2) ? inputs[b * (NNODES * 2) + n * 2 + f]
                       : state[(size_t)b * SN + n * HID + (f - 2)];
    }
    ushort ob[8];
#pragma unroll
    for (int j = 0; j < 8; ++j) ob[j] = f2bf(v[j]);
    uint4 r;
    r.x = (uint32_t)ob[0] | ((uint32_t)ob[1] << 16);
    r.y = (uint32_t)ob[2] | ((uint32_t)ob[3] << 16);
    r.z = (uint32_t)ob[4] | ((uint32_t)ob[5] << 16);
    r.w = (uint32_t)ob[6] | ((uint32_t)ob[7] << 16);
    *(uint4*)(Xs0 + (size_t)n * CCH + rc * 8) = r;
    size_t base = ((size_t)n * 16 + b0) * ROWE + f;   // slice0: kk = f
#pragma unroll
    for (int j = 0; j < 8; ++j) x_all[base + (size_t)j * ROWE] = ob[j];
}

// ---------------- SPMM: [n][f][b] contiguous gathers, dual-write K-major ----------------

static __device__ __forceinline__ void fma8(float* acc, uint4 d, float v) {
    acc[0] += v * bf2f((ushort)(d.x));  acc[1] += v * bf2f((ushort)(d.x >> 16));
    acc[2] += v * bf2f((ushort)(d.y));  acc[3] += v * bf2f((ushort)(d.y >> 16));
    acc[4] += v * bf2f((ushort)(d.z));  acc[5] += v * bf2f((ushort)(d.z >> 16));
    acc[6] += v * bf2f((ushort)(d.w));  acc[7] += v * bf2f((ushort)(d.w >> 16));
}

static __device__ __forceinline__ void emit_chunk(const float* acc, int ch, int n,
                                                  const ushort* xp, ushort* yout,
                                                  ushort* xall, int koff,
                                                  float alpha, float beta) {
    float o[8];
    if (beta != 0.f) {
        uint4 p = *(const uint4*)(xp + (size_t)n * CCH + ch * 8);
        o[0] = alpha * acc[0] + beta * bf2f((ushort)(p.x));
        o[1] = alpha * acc[1] + beta * bf2f((ushort)(p.x >> 16));
        o[2] = alpha * acc[2] + beta * bf2f((ushort)(p.y));
        o[3] = alpha * acc[3] + beta * bf2f((ushort)(p.y >> 16));
        o[4] = alpha * acc[4] + beta * bf2f((ushort)(p.z));
        o[5] = alpha * acc[5] + beta * bf2f((ushort)(p.z >> 16));
        o[6] = alpha * acc[6] + beta * bf2f((ushort)(p.w));
        o[7] = alpha * acc[7] + beta * bf2f((ushort)(p.w >> 16));
    } else {
#pragma unroll
        for (int j = 0; j < 8; ++j) o[j] = alpha * acc[j];
    }
    ushort ob[8];
#pragma unroll
    for (int j = 0; j < 8; ++j) ob[j] = f2bf(o[j]);
    if (yout) {
        uint4 r;
        r.x = (uint32_t)ob[0] | ((uint32_t)ob[1] << 16);
        r.y = (uint32_t)ob[2] | ((uint32_t)ob[3] << 16);
        r.z = (uint32_t)ob[4] | ((uint32_t)ob[5] << 16);
        r.w = (uint32_t)ob[6] | ((uint32_t)ob[7] << 16);
        *(uint4*)(yout + (size_t)n * CCH + ch * 8) = r;
    }
    int f = ch >> 1, b0 = (ch & 1) * 8;
    size_t base = ((size_t)n * 16 + b0) * ROWE + koff + f;
#pragma unroll
    for (int j = 0; j < 8; ++j) xall[base + (size_t)j * ROWE] = ob[j];
}

__global__ __launch_bounds__(128) void spmm_kernel(const int* __restrict__ rowptr,
                                                   const int* __restrict__ cols,
                                                   const float* __restrict__ vals,
                                                   const ushort* __restrict__ xin,
                                                   const ushort* __restrict__ xp,
                                                   ushort* __restrict__ yout,
                                                   ushort* __restrict__ xall, int koff,
                                                   float alpha, float beta) {
    int n = blockIdx.x;
    int t = threadIdx.x;
    int lane = t & 63;
    int off0 = t * 8;
    int off1 = 1024 + t * 8;
    bool tail = t < 4;  // chunks 128..131

    int s = rowptr[n], e = rowptr[n + 1];
    float a0[8] = {0, 0, 0, 0, 0, 0, 0, 0};
    float a1[8] = {0, 0, 0, 0, 0, 0, 0, 0};

    for (int base = s; base < e; base += 64) {
        int rem = e - base;
        if (rem > 64) rem = 64;
        int mc = 0; float mv = 0.f;
        if (lane < rem) { mc = cols[base + lane]; mv = vals[base + lane]; }
        for (int j = 0; j < rem; j += 4) {
            int   c0 = __shfl(mc, j);
            float v0 = __shfl(mv, j);
            int   c1 = __shfl(mc, (j + 1) & 63);
            float v1 = (j + 1 < rem) ? __shfl(mv, (j + 1) & 63) : 0.f;
            int   c2 = __shfl(mc, (j + 2) & 63);
            float v2 = (j + 2 < rem) ? __shfl(mv, (j + 2) & 63) : 0.f;
            int   c3 = __shfl(mc, (j + 3) & 63);
            float v3 = (j + 3 < rem) ? __shfl(mv, (j + 3) & 63) : 0.f;
            const ushort* s0 = xin + (size_t)c0 * CCH;
            const ushort* s1 = xin + (size_t)c1 * CCH;
            const ushort* s2 = xin + (size_t)c2 * CCH;
            const ushort* s3 = xin + (size_t)c3 * CCH;
            uint4 d0 = *(const uint4*)(s0 + off0);
            uint4 d1 = *(const uint4*)(s1 + off0);
            uint4 d2 = *(const uint4*)(s2 + off0);
            uint4 d3 = *(const uint4*)(s3 + off0);
            fma8(a0, d0, v0); fma8(a0, d1, v1); fma8(a0, d2, v2); fma8(a0, d3, v3);
            if (tail) {
                uint4 e0 = *(const uint4*)(s0 + off1);
                uint4 e1 = *(const uint4*)(s1 + off1);
                uint4 e2 = *(const uint4*)(s2 + off1);
                uint4 e3 = *(const uint4*)(s3 + off1);
                fma8(a1, e0, v0); fma8(a1, e1, v1); fma8(a1, e2, v2); fma8(a1, e3, v3);
            }
        }
    }
    emit_chunk(a0, t, n, xp, yout, xall, koff, alpha, beta);
    if (tail) emit_chunk(a1, 128 + t, n, xp, yout, xall, koff, alpha, beta);
}

// ---------------- gate GEMM: 512 thr = 8 waves = col tiles 0..7; A direct from x_all ----------------
// barrier between MFMA-reads and slice0 writes of the same node (race fix).

__global__ __launch_bounds__(512) void gate_mfma(const ushort* __restrict__ x_all,
                                                 const ushort* __restrict__ WgT,
                                                 const float* __restrict__ bg,
                                                 const ushort* __restrict__ st,
                                                 float* __restrict__ U,
                                                 ushort* __restrict__ Xs0,
                                                 ushort* __restrict__ x_mut) {
    int tid = threadIdx.x;
    int wave = tid >> 6, lane = tid & 63;
    int l15 = lane & 15, quad = lane >> 4;
    int c = wave * 16 + l15;         // 0..127

    bf16x8 w[12];
#pragma unroll
    for (int k = 0; k < 12; ++k)
        w[k] = *(const bf16x8*)(WgT + (size_t)c * ROWE + k * 32 + quad * 8);
    float bias = bg[c];

    int n0 = blockIdx.x * GN;
    bf16x8 a[12], an[12];
    {
        const ushort* Ab = x_all + ((size_t)n0 * 16 + l15) * ROWE + quad * 8;
#pragma unroll
        for (int k = 0; k < 12; ++k) a[k] = *(const bf16x8*)(Ab + k * 32);
    }

    for (int g = 0; g < GN; ++g) {
        int n = n0 + g;
        if (g + 1 < GN) {
            const ushort* Ab = x_all + ((size_t)(n + 1) * 16 + l15) * ROWE + quad * 8;
#pragma unroll
            for (int k = 0; k < 12; ++k) an[k] = *(const bf16x8*)(Ab + k * 32);
        }
        f32x4 acc = {0.f, 0.f, 0.f, 0.f};
#pragma unroll
        for (int k = 0; k < 12; ++k)
            acc = __builtin_amdgcn_mfma_f32_16x16x32_bf16(a[k], w[k], acc, 0, 0, 0);

        __syncthreads();  // all waves' reads of node g (and prefetch of g+1) complete

#pragma unroll
        for (int r = 0; r < 4; ++r) {
            int b = quad * 4 + r;
            size_t row = (size_t)n * 16 + b;
            float v = 1.f / (1.f + __expf(-(acc[r] + bias)));
            if (wave < 4) {   // cols 0..63: r-gate -> xc slice0, both layouts
                float s = bf2f(st[row * 64 + c]);
                ushort rs = f2bf(v * s);
                Xs0[(size_t)n * CCH + (2 + c) * 16 + b] = rs;
                x_mut[row * ROWE + 2 + c] = rs;
            } else {          // cols 64..127: u-gate (fp32, row-major)
                U[row * 64 + (c - 64)] = v;
            }
        }
#pragma unroll
        for (int k = 0; k < 12; ++k) a[k] = an[k];
    }
}

// ---------------- cand GEMM: 256 thr = 4 waves = col tiles 0..3 + GRU update ----------------

__global__ __launch_bounds__(256) void cand_mfma(const ushort* __restrict__ x_all,
                                                 const ushort* __restrict__ WcT,
                                                 const float* __restrict__ bc,
                                                 const ushort* __restrict__ st,
                                                 const float* __restrict__ U,
                                                 float* __restrict__ out) {
    int tid = threadIdx.x;
    int wave = tid >> 6, lane = tid & 63;
    int l15 = lane & 15, quad = lane >> 4;
    int c = wave * 16 + l15;         // 0..63

    bf16x8 w[12];
#pragma unroll
    for (int k = 0; k < 12; ++k)
        w[k] = *(const bf16x8*)(WcT + (size_t)c * ROWE + k * 32 + quad * 8);
    float bias = bc[c];

    int n0 = blockIdx.x * GN;
    bf16x8 a[12], an[12];
    {
        const ushort* Ab = x_all + ((size_t)n0 * 16 + l15) * ROWE + quad * 8;
#pragma unroll
        for (int k = 0; k < 12; ++k) a[k] = *(const bf16x8*)(Ab + k * 32);
    }

    for (int g = 0; g < GN; ++g) {
        int n = n0 + g;
        if (g + 1 < GN) {
            const ushort* Ab = x_all + ((size_t)(n + 1) * 16 + l15) * ROWE + quad * 8;
#pragma unroll
            for (int k = 0; k < 12; ++k) an[k] = *(const bf16x8*)(Ab + k * 32);
        }
        f32x4 acc = {0.f, 0.f, 0.f, 0.f};
#pragma unroll
        for (int k = 0; k < 12; ++k)
            acc = __builtin_amdgcn_mfma_f32_16x16x32_bf16(a[k], w[k], acc, 0, 0, 0);

#pragma unroll
        for (int r = 0; r < 4; ++r) {
            int b = quad * 4 + r;
            size_t row = (size_t)n * 16 + b;
            float pre = acc[r] + bias;
            float cv = 1.f - 2.f / (__expf(2.f * pre) + 1.f);  // tanh
            float uv = U[row * 64 + c];
            float s = bf2f(st[row * 64 + c]);
            float ns = uv * s + (1.f - uv) * cv;
            size_t idx = (size_t)b * SN + (size_t)n * HID + c;
            out[idx] = ns;
            out[OUTHALF + idx] = ns;
        }
#pragma unroll
        for (int k = 0; k < 12; ++k) a[k] = an[k];
    }
}

// ---------------- launch ----------------

extern "C" void kernel_launch(void* const* d_in, const int* in_sizes, int n_in,
                              void* d_out, int out_size, void* d_ws, size_t ws_size,
                              hipStream_t stream) {
    const float* inputs = (const float*)d_in[0];
    const float* state  = (const float*)d_in[1];
    const int*   esrc   = (const int*)d_in[2];
    const int*   edst   = (const int*)d_in[3];
    const float* v1     = (const float*)d_in[4];
    const float* v2     = (const float*)d_in[5];
    const float* Wg     = (const float*)d_in[6];
    const float* bg     = (const float*)d_in[7];
    const float* Wc     = (const float*)d_in[8];
    const float* bc     = (const float*)d_in[9];
    float* out = (float*)d_out;

    char* ws = (char*)d_ws;
    size_t off = 0;
    auto alloc = [&](size_t bytes) -> void* {
        void* p = ws + off;
        off += (bytes + 255) & ~(size_t)255;
        return p;
    };
    ushort* S0     = (ushort*)alloc((size_t)NFB * 2);             // 17.3 MB  slice0 [n][f][b]
    ushort* S1     = (ushort*)alloc((size_t)NFB * 2);             // 17.3 MB  slice1
    ushort* S3     = (ushort*)alloc((size_t)NFB * 2);             // 17.3 MB  slice3
    ushort* x_all  = (ushort*)alloc((size_t)NNODES * 16 * ROWE * 2); // 100.7 MB K-major
    float*  U      = (float*)alloc((size_t)NNODES * 16 * 64 * 4); // 33.5 MB [row][c]
    ushort* st     = (ushort*)alloc((size_t)NNODES * 16 * 64 * 2);// 16.8 MB [row][c]
    ushort* WgT    = (ushort*)alloc((size_t)128 * ROWE * 2);
    ushort* WcT    = (ushort*)alloc((size_t)64 * ROWE * 2);
    int*   counts1 = (int*)alloc(NNODES * 4);
    int*   counts2 = (int*)alloc(NNODES * 4);
    int*   rowptr1 = (int*)alloc((NNODES + 1) * 4);
    int*   rowptr2 = (int*)alloc((NNODES + 1) * 4);
    int*   cursor1 = (int*)alloc(NNODES * 4);
    int*   cursor2 = (int*)alloc(NNODES * 4);
    int*   cols1   = (int*)alloc(NEDGE * 4);
    int*   cols2   = (int*)alloc(NEDGE * 4);
    float* valsC1  = (float*)alloc(NEDGE * 4);
    float* valsC2  = (float*)alloc(NEDGE * 4);

    // CSR build (graph shared by both diff_convs)
    zero_counts_kernel<<<(NNODES + 255) / 256, 256, 0, stream>>>(counts1, counts2);
    hist_kernel<<<(NEDGE + 255) / 256, 256, 0, stream>>>(esrc, edst, counts1, counts2);
    scan_kernel<<<1, 1024, 0, stream>>>(counts1, rowptr1, cursor1);
    scan_kernel<<<1, 1024, 0, stream>>>(counts2, rowptr2, cursor2);
    scatter_kernel<<<(NEDGE + 255) / 256, 256, 0, stream>>>(esrc, edst, v1, v2,
                                                            cursor1, cursor2,
                                                            cols1, valsC1, cols2, valsC2);

    convert_w_kernel<<<(192 * ROWE + 255) / 256, 256, 0, stream>>>(Wg, Wc, WgT, WcT);
    st_build_kernel<<<((SN * 16 / 4) + 255) / 256, 256, 0, stream>>>(state, st);
    init_x0_kernel<<<(NFB / 8 + 255) / 256, 256, 0, stream>>>(inputs, state, S0, x_all);

    // diff_conv #1: slice1(koff 72), slice2(144, dual-only), slice3(216), slice4(288, dual-only)
    spmm_kernel<<<NNODES, 128, 0, stream>>>(rowptr1, cols1, valsC1, S0, S0, S1, x_all, 72, 1.f, 0.f);
    spmm_kernel<<<NNODES, 128, 0, stream>>>(rowptr1, cols1, valsC1, S1, S0, (ushort*)nullptr, x_all, 144, 2.f, -1.f);
    spmm_kernel<<<NNODES, 128, 0, stream>>>(rowptr2, cols2, valsC2, S0, S0, S3, x_all, 216, 1.f, 0.f);
    spmm_kernel<<<NNODES, 128, 0, stream>>>(rowptr2, cols2, valsC2, S3, S0, (ushort*)nullptr, x_all, 288, 2.f, -1.f);

    // gate GEMM: writes U, overwrites slice0 state-part (both layouts) with r*state
    gate_mfma<<<NNODES / GN, 512, 0, stream>>>(x_all, WgT, bg, st, U, S0, x_all);

    // diff_conv #2 on xc
    spmm_kernel<<<NNODES, 128, 0, stream>>>(rowptr1, cols1, valsC1, S0, S0, S1, x_all, 72, 1.f, 0.f);
    spmm_kernel<<<NNODES, 128, 0, stream>>>(rowptr1, cols1, valsC1, S1, S0, (ushort*)nullptr, x_all, 144, 2.f, -1.f);
    spmm_kernel<<<NNODES, 128, 0, stream>>>(rowptr2, cols2, valsC2, S0, S0, S3, x_all, 216, 1.f, 0.f);
    spmm_kernel<<<NNODES, 128, 0, stream>>>(rowptr2, cols2, valsC2, S3, S0, (ushort*)nullptr, x_all, 288, 2.f, -1.f);

    // cand GEMM + tanh + GRU update + duplicated output
    cand_mfma<<<NNODES / GN, 256, 0, stream>>>(x_all, WcT, bc, st, U, out);
}

// Round 6
// 678.740 us; speedup vs baseline: 1.4256x; 1.0397x over previous
//
#include <hip/hip_runtime.h>
#include <cstddef>
#include <cstdint>

#define NNODES 8192
#define HID    64
#define NEDGE  131072
#define SN     524288    // NNODES * HID (per-batch stride in state/out)
#define OUTHALF 8388608  // BATCH * SN
#define CCH    1056      // 66 features * 16 batch, per node per slice
#define NFB    8650752   // NNODES * CCH
#define ROWE   384       // K-major padded row: 5*72 + 24 tail
#define SLICE  72
#define GN     8         // nodes per GEMM block

typedef __attribute__((ext_vector_type(8))) short bf16x8;
typedef __attribute__((ext_vector_type(4))) float f32x4;

static __device__ __forceinline__ float bf2f(ushort u) {
    union { uint32_t i; float f; } c; c.i = ((uint32_t)u) << 16; return c.f;
}
static __device__ __forceinline__ ushort f2bf(float f) {
    union { float f; uint32_t i; } c; c.f = f;
    uint32_t lsb = (c.i >> 16) & 1;
    return (ushort)((c.i + 0x7fffu + lsb) >> 16);
}

// ---------------- CSR construction ----------------

__global__ void zero_counts_kernel(int* __restrict__ c1, int* __restrict__ c2) {
    int i = blockIdx.x * 256 + threadIdx.x;
    if (i < NNODES) { c1[i] = 0; c2[i] = 0; }
}

__global__ void hist_kernel(const int* __restrict__ src, const int* __restrict__ dst,
                            int* __restrict__ c1, int* __restrict__ c2) {
    int e = blockIdx.x * 256 + threadIdx.x;
    if (e < NEDGE) {
        atomicAdd(&c1[src[e]], 1);
        atomicAdd(&c2[dst[e]], 1);
    }
}

__global__ __launch_bounds__(1024) void scan_kernel(const int* __restrict__ counts,
                                                    int* __restrict__ rowptr,
                                                    int* __restrict__ cursor) {
    __shared__ int sh[1024];
    int tid = threadIdx.x;
    int base = tid * 8;
    int local[8];
    int sum = 0;
#pragma unroll
    for (int j = 0; j < 8; ++j) { local[j] = counts[base + j]; sum += local[j]; }
    sh[tid] = sum;
    __syncthreads();
    for (int off = 1; off < 1024; off <<= 1) {
        int v = (tid >= off) ? sh[tid - off] : 0;
        __syncthreads();
        sh[tid] += v;
        __syncthreads();
    }
    int p = sh[tid] - sum;
#pragma unroll
    for (int j = 0; j < 8; ++j) {
        cursor[base + j] = p;
        p += local[j];
        rowptr[base + j + 1] = p;
    }
    if (tid == 0) rowptr[0] = 0;
}

__global__ void scatter_kernel(const int* __restrict__ src, const int* __restrict__ dst,
                               const float* __restrict__ v1, const float* __restrict__ v2,
                               int* __restrict__ cur1, int* __restrict__ cur2,
                               int* __restrict__ cols1, float* __restrict__ valsC1,
                               int* __restrict__ cols2, float* __restrict__ valsC2) {
    int e = blockIdx.x * 256 + threadIdx.x;
    if (e < NEDGE) {
        int r1 = src[e];
        int p1 = atomicAdd(&cur1[r1], 1);
        cols1[p1] = dst[e];
        valsC1[p1] = v1[e];
        int r2 = dst[e];
        int p2 = atomicAdd(&cur2[r2], 1);
        cols2[p2] = src[e];
        valsC2[p2] = v2[e];
    }
}

// ------- weight: W[k_ref=f*5+m][C] -> WT[col][kk=m*72+f] bf16, pads (f>=66, kk>=360) zero -------

__global__ void convert_w_kernel(const float* __restrict__ Wg, const float* __restrict__ Wc,
                                 ushort* __restrict__ WgT, ushort* __restrict__ WcT) {
    int i = blockIdx.x * 256 + threadIdx.x;
    if (i >= 192 * ROWE) return;
    int col = i / ROWE, kk = i - col * ROWE;
    int m = kk / SLICE, f = kk - m * SLICE;
    bool real = (m < 5) && (f < 66);
    if (col < 128) {
        WgT[col * ROWE + kk] = real ? f2bf(Wg[(f * 5 + m) * 128 + col]) : (ushort)0;
    } else {
        int c = col - 128;
        WcT[c * ROWE + kk] = real ? f2bf(Wc[(f * 5 + m) * 64 + c]) : (ushort)0;
    }
}

// ---------------- st[row=(n,b)][c] = bf16(state[b][n][c]) ----------------

__global__ void st_build_kernel(const float* __restrict__ state, ushort* __restrict__ st) {
    int i = blockIdx.x * 256 + threadIdx.x;
    if (i >= (SN * 16) / 4) return;
    size_t idx4 = (size_t)i * 4;
    int b = (int)(idx4 >> 19);          // SN = 2^19
    int r = (int)(idx4 & (SN - 1));
    int n = r >> 6, c = r & 63;
    float4 v = *(const float4*)(state + idx4);
    uint2 o;
    o.x = (uint32_t)f2bf(v.x) | ((uint32_t)f2bf(v.y) << 16);
    o.y = (uint32_t)f2bf(v.z) | ((uint32_t)f2bf(v.w) << 16);
    *(uint2*)(st + ((size_t)((n << 4) + b)) * 64 + c) = o;
}

// ------- init x0: slice0 [n][f][b] contiguous + dual-write K-major x_all[row][f] -------

__global__ void init_x0_kernel(const float* __restrict__ inputs, const float* __restrict__ state,
                               ushort* __restrict__ Xs0, ushort* __restrict__ x_all) {
    int i = blockIdx.x * 256 + threadIdx.x;
    if (i >= NFB / 8) return;
    int n = i / 132, rc = i - n * 132;
    int f = rc >> 1, b0 = (rc & 1) * 8;
    float v[8];
#pragma unroll
    for (int j = 0; j < 8; ++j) {
        int b = b0 + j;
        v[j] = (f < 2) ? inputs[b * (NNODES * 2) + n * 2 + f]
                       : state[(size_t)b * SN + n * HID + (f - 2)];
    }
    ushort ob[8];
#pragma unroll
    for (int j = 0; j < 8; ++j) ob[j] = f2bf(v[j]);
    uint4 r;
    r.x = (uint32_t)ob[0] | ((uint32_t)ob[1] << 16);
    r.y = (uint32_t)ob[2] | ((uint32_t)ob[3] << 16);
    r.z = (uint32_t)ob[4] | ((uint32_t)ob[5] << 16);
    r.w = (uint32_t)ob[6] | ((uint32_t)ob[7] << 16);
    *(uint4*)(Xs0 + (size_t)n * CCH + rc * 8) = r;
    size_t base = ((size_t)n * 16 + b0) * ROWE + f;   // slice0: kk = f
#pragma unroll
    for (int j = 0; j < 8; ++j) x_all[base + (size_t)j * ROWE] = ob[j];
}

// ---------------- SPMM: [n][f][b] contiguous gathers; K-major emit via LDS ----------------

static __device__ __forceinline__ void fma8(float* acc, uint4 d, float v) {
    acc[0] += v * bf2f((ushort)(d.x));  acc[1] += v * bf2f((ushort)(d.x >> 16));
    acc[2] += v * bf2f((ushort)(d.y));  acc[3] += v * bf2f((ushort)(d.y >> 16));
    acc[4] += v * bf2f((ushort)(d.z));  acc[5] += v * bf2f((ushort)(d.z >> 16));
    acc[6] += v * bf2f((ushort)(d.w));  acc[7] += v * bf2f((ushort)(d.w >> 16));
}

// kt: LDS [16][72] tile (144-B rows, uint4-aligned)
static __device__ __forceinline__ void emit_chunk(const float* acc, int ch, int n,
                                                  const ushort* xp, ushort* yout,
                                                  ushort* kt,
                                                  float alpha, float beta) {
    float o[8];
    if (beta != 0.f) {
        uint4 p = *(const uint4*)(xp + (size_t)n * CCH + ch * 8);
        o[0] = alpha * acc[0] + beta * bf2f((ushort)(p.x));
        o[1] = alpha * acc[1] + beta * bf2f((ushort)(p.x >> 16));
        o[2] = alpha * acc[2] + beta * bf2f((ushort)(p.y));
        o[3] = alpha * acc[3] + beta * bf2f((ushort)(p.y >> 16));
        o[4] = alpha * acc[4] + beta * bf2f((ushort)(p.z));
        o[5] = alpha * acc[5] + beta * bf2f((ushort)(p.z >> 16));
        o[6] = alpha * acc[6] + beta * bf2f((ushort)(p.w));
        o[7] = alpha * acc[7] + beta * bf2f((ushort)(p.w >> 16));
    } else {
#pragma unroll
        for (int j = 0; j < 8; ++j) o[j] = alpha * acc[j];
    }
    ushort ob[8];
#pragma unroll
    for (int j = 0; j < 8; ++j) ob[j] = f2bf(o[j]);
    if (yout) {
        uint4 r;
        r.x = (uint32_t)ob[0] | ((uint32_t)ob[1] << 16);
        r.y = (uint32_t)ob[2] | ((uint32_t)ob[3] << 16);
        r.z = (uint32_t)ob[4] | ((uint32_t)ob[5] << 16);
        r.w = (uint32_t)ob[6] | ((uint32_t)ob[7] << 16);
        *(uint4*)(yout + (size_t)n * CCH + ch * 8) = r;
    }
    int f = ch >> 1, b0 = (ch & 1) * 8;
#pragma unroll
    for (int j = 0; j < 8; ++j) kt[(b0 + j) * SLICE + f] = ob[j];
}

__global__ __launch_bounds__(128) void spmm_kernel(const int* __restrict__ rowptr,
                                                   const int* __restrict__ cols,
                                                   const float* __restrict__ vals,
                                                   const ushort* __restrict__ xin,
                                                   const ushort* __restrict__ xp,
                                                   ushort* __restrict__ yout,
                                                   ushort* __restrict__ xall, int koff,
                                                   float alpha, float beta) {
    __shared__ __align__(16) ushort kt[16 * SLICE];
    int n = blockIdx.x;
    int t = threadIdx.x;
    int lane = t & 63;
    int off0 = t * 8;
    int off1 = 1024 + t * 8;
    bool tail = t < 4;  // chunks 128..131

    // zero pad cols f=66..71 (never written by chunks; must be finite for MFMA)
    if (t < 96) kt[(t / 6) * SLICE + 66 + (t % 6)] = 0;

    int s = rowptr[n], e = rowptr[n + 1];
    float a0[8] = {0, 0, 0, 0, 0, 0, 0, 0};
    float a1[8] = {0, 0, 0, 0, 0, 0, 0, 0};

    for (int base = s; base < e; base += 64) {
        int rem = e - base;
        if (rem > 64) rem = 64;
        int mc = 0; float mv = 0.f;
        if (lane < rem) { mc = cols[base + lane]; mv = vals[base + lane]; }
        for (int j = 0; j < rem; j += 4) {
            int   c0 = __shfl(mc, j);
            float v0 = __shfl(mv, j);
            int   c1 = __shfl(mc, (j + 1) & 63);
            float v1 = (j + 1 < rem) ? __shfl(mv, (j + 1) & 63) : 0.f;
            int   c2 = __shfl(mc, (j + 2) & 63);
            float v2 = (j + 2 < rem) ? __shfl(mv, (j + 2) & 63) : 0.f;
            int   c3 = __shfl(mc, (j + 3) & 63);
            float v3 = (j + 3 < rem) ? __shfl(mv, (j + 3) & 63) : 0.f;
            const ushort* s0 = xin + (size_t)c0 * CCH;
            const ushort* s1 = xin + (size_t)c1 * CCH;
            const ushort* s2 = xin + (size_t)c2 * CCH;
            const ushort* s3 = xin + (size_t)c3 * CCH;
            uint4 d0 = *(const uint4*)(s0 + off0);
            uint4 d1 = *(const uint4*)(s1 + off0);
            uint4 d2 = *(const uint4*)(s2 + off0);
            uint4 d3 = *(const uint4*)(s3 + off0);
            fma8(a0, d0, v0); fma8(a0, d1, v1); fma8(a0, d2, v2); fma8(a0, d3, v3);
            if (tail) {
                uint4 e0 = *(const uint4*)(s0 + off1);
                uint4 e1 = *(const uint4*)(s1 + off1);
                uint4 e2 = *(const uint4*)(s2 + off1);
                uint4 e3 = *(const uint4*)(s3 + off1);
                fma8(a1, e0, v0); fma8(a1, e1, v1); fma8(a1, e2, v2); fma8(a1, e3, v3);
            }
        }
    }
    emit_chunk(a0, t, n, xp, yout, kt, alpha, beta);
    if (tail) emit_chunk(a1, 128 + t, n, xp, yout, kt, alpha, beta);

    __syncthreads();
    // coalesced K-major store: 144 uint4 = 16 rows x 9 pieces
    for (int i = t; i < 144; i += 128) {
        int b = i / 9, f8 = (i - b * 9) * 8;
        uint4 d = *(const uint4*)(kt + b * SLICE + f8);
        *(uint4*)(xall + ((size_t)n * 16 + b) * ROWE + koff + f8) = d;
    }
}

// ---------------- gate GEMM: 512 thr = 8 waves = col tiles 0..7; A direct from x_all ----------------
// per-node barrier between all waves' A-loads and slice0 writes (in-place xc update).

__global__ __launch_bounds__(512, 2) void gate_mfma(const ushort* __restrict__ x_all,
                                                    const ushort* __restrict__ WgT,
                                                    const float* __restrict__ bg,
                                                    const ushort* __restrict__ st,
                                                    float* __restrict__ U,
                                                    ushort* __restrict__ Xs0,
                                                    ushort* __restrict__ x_mut) {
    int tid = threadIdx.x;
    int wave = tid >> 6, lane = tid & 63;
    int l15 = lane & 15, quad = lane >> 4;
    int c = wave * 16 + l15;         // 0..127

    bf16x8 w[12];
#pragma unroll
    for (int k = 0; k < 12; ++k)
        w[k] = *(const bf16x8*)(WgT + (size_t)c * ROWE + k * 32 + quad * 8);
    float bias = bg[c];

    int n0 = blockIdx.x * GN;
    for (int g = 0; g < GN; ++g) {
        int n = n0 + g;
        const ushort* Ab = x_all + ((size_t)n * 16 + l15) * ROWE + quad * 8;
        bf16x8 a[12];
#pragma unroll
        for (int k = 0; k < 12; ++k) a[k] = *(const bf16x8*)(Ab + k * 32);

        __syncthreads();  // all waves loaded node g before anyone writes its slice0

        f32x4 acc = {0.f, 0.f, 0.f, 0.f};
#pragma unroll
        for (int k = 0; k < 12; ++k)
            acc = __builtin_amdgcn_mfma_f32_16x16x32_bf16(a[k], w[k], acc, 0, 0, 0);

#pragma unroll
        for (int r = 0; r < 4; ++r) {
            int b = quad * 4 + r;
            size_t row = (size_t)n * 16 + b;
            float v = 1.f / (1.f + __expf(-(acc[r] + bias)));
            if (wave < 4) {   // cols 0..63: r-gate -> xc slice0, both layouts
                float s = bf2f(st[row * 64 + c]);
                ushort rs = f2bf(v * s);
                Xs0[(size_t)n * CCH + (2 + c) * 16 + b] = rs;
                x_mut[row * ROWE + 2 + c] = rs;
            } else {          // cols 64..127: u-gate (fp32, row-major)
                U[row * 64 + (c - 64)] = v;
            }
        }
    }
}

// ---------------- cand GEMM: 256 thr = 4 waves = col tiles 0..3 + GRU update ----------------

__global__ __launch_bounds__(256, 2) void cand_mfma(const ushort* __restrict__ x_all,
                                                    const ushort* __restrict__ WcT,
                                                    const float* __restrict__ bc,
                                                    const ushort* __restrict__ st,
                                                    const float* __restrict__ U,
                                                    float* __restrict__ out) {
    int tid = threadIdx.x;
    int wave = tid >> 6, lane = tid & 63;
    int l15 = lane & 15, quad = lane >> 4;
    int c = wave * 16 + l15;         // 0..63

    bf16x8 w[12];
#pragma unroll
    for (int k = 0; k < 12; ++k)
        w[k] = *(const bf16x8*)(WcT + (size_t)c * ROWE + k * 32 + quad * 8);
    float bias = bc[c];

    int n0 = blockIdx.x * GN;
    for (int g = 0; g < GN; ++g) {
        int n = n0 + g;
        const ushort* Ab = x_all + ((size_t)n * 16 + l15) * ROWE + quad * 8;
        bf16x8 a[12];
#pragma unroll
        for (int k = 0; k < 12; ++k) a[k] = *(const bf16x8*)(Ab + k * 32);

        f32x4 acc = {0.f, 0.f, 0.f, 0.f};
#pragma unroll
        for (int k = 0; k < 12; ++k)
            acc = __builtin_amdgcn_mfma_f32_16x16x32_bf16(a[k], w[k], acc, 0, 0, 0);

#pragma unroll
        for (int r = 0; r < 4; ++r) {
            int b = quad * 4 + r;
            size_t row = (size_t)n * 16 + b;
            float pre = acc[r] + bias;
            float cv = 1.f - 2.f / (__expf(2.f * pre) + 1.f);  // tanh
            float uv = U[row * 64 + c];
            float s = bf2f(st[row * 64 + c]);
            float ns = uv * s + (1.f - uv) * cv;
            size_t idx = (size_t)b * SN + (size_t)n * HID + c;
            out[idx] = ns;
            out[OUTHALF + idx] = ns;
        }
    }
}

// ---------------- launch ----------------

extern "C" void kernel_launch(void* const* d_in, const int* in_sizes, int n_in,
                              void* d_out, int out_size, void* d_ws, size_t ws_size,
                              hipStream_t stream) {
    const float* inputs = (const float*)d_in[0];
    const float* state  = (const float*)d_in[1];
    const int*   esrc   = (const int*)d_in[2];
    const int*   edst   = (const int*)d_in[3];
    const float* v1     = (const float*)d_in[4];
    const float* v2     = (const float*)d_in[5];
    const float* Wg     = (const float*)d_in[6];
    const float* bg     = (const float*)d_in[7];
    const float* Wc     = (const float*)d_in[8];
    const float* bc     = (const float*)d_in[9];
    float* out = (float*)d_out;

    char* ws = (char*)d_ws;
    size_t off = 0;
    auto alloc = [&](size_t bytes) -> void* {
        void* p = ws + off;
        off += (bytes + 255) & ~(size_t)255;
        return p;
    };
    ushort* S0     = (ushort*)alloc((size_t)NFB * 2);             // 17.3 MB  slice0 [n][f][b]
    ushort* S1     = (ushort*)alloc((size_t)NFB * 2);             // 17.3 MB  slice1
    ushort* S3     = (ushort*)alloc((size_t)NFB * 2);             // 17.3 MB  slice3
    ushort* x_all  = (ushort*)alloc((size_t)NNODES * 16 * ROWE * 2); // 100.7 MB K-major
    float*  U      = (float*)alloc((size_t)NNODES * 16 * 64 * 4); // 33.5 MB [row][c]
    ushort* st     = (ushort*)alloc((size_t)NNODES * 16 * 64 * 2);// 16.8 MB [row][c]
    ushort* WgT    = (ushort*)alloc((size_t)128 * ROWE * 2);
    ushort* WcT    = (ushort*)alloc((size_t)64 * ROWE * 2);
    int*   counts1 = (int*)alloc(NNODES * 4);
    int*   counts2 = (int*)alloc(NNODES * 4);
    int*   rowptr1 = (int*)alloc((NNODES + 1) * 4);
    int*   rowptr2 = (int*)alloc((NNODES + 1) * 4);
    int*   cursor1 = (int*)alloc(NNODES * 4);
    int*   cursor2 = (int*)alloc(NNODES * 4);
    int*   cols1   = (int*)alloc(NEDGE * 4);
    int*   cols2   = (int*)alloc(NEDGE * 4);
    float* valsC1  = (float*)alloc(NEDGE * 4);
    float* valsC2  = (float*)alloc(NEDGE * 4);

    // CSR build (graph shared by both diff_convs)
    zero_counts_kernel<<<(NNODES + 255) / 256, 256, 0, stream>>>(counts1, counts2);
    hist_kernel<<<(NEDGE + 255) / 256, 256, 0, stream>>>(esrc, edst, counts1, counts2);
    scan_kernel<<<1, 1024, 0, stream>>>(counts1, rowptr1, cursor1);
    scan_kernel<<<1, 1024, 0, stream>>>(counts2, rowptr2, cursor2);
    scatter_kernel<<<(NEDGE + 255) / 256, 256, 0, stream>>>(esrc, edst, v1, v2,
                                                            cursor1, cursor2,
                                                            cols1, valsC1, cols2, valsC2);

    convert_w_kernel<<<(192 * ROWE + 255) / 256, 256, 0, stream>>>(Wg, Wc, WgT, WcT);
    st_build_kernel<<<((SN * 16 / 4) + 255) / 256, 256, 0, stream>>>(state, st);
    init_x0_kernel<<<(NFB / 8 + 255) / 256, 256, 0, stream>>>(inputs, state, S0, x_all);

    // diff_conv #1: slice1(koff 72), slice2(144, K-major only), slice3(216), slice4(288, K-major only)
    spmm_kernel<<<NNODES, 128, 0, stream>>>(rowptr1, cols1, valsC1, S0, S0, S1, x_all, 72, 1.f, 0.f);
    spmm_kernel<<<NNODES, 128, 0, stream>>>(rowptr1, cols1, valsC1, S1, S0, (ushort*)nullptr, x_all, 144, 2.f, -1.f);
    spmm_kernel<<<NNODES, 128, 0, stream>>>(rowptr2, cols2, valsC2, S0, S0, S3, x_all, 216, 1.f, 0.f);
    spmm_kernel<<<NNODES, 128, 0, stream>>>(rowptr2, cols2, valsC2, S3, S0, (ushort*)nullptr, x_all, 288, 2.f, -1.f);

    // gate GEMM: writes U, overwrites slice0 state-part (both layouts) with r*state
    gate_mfma<<<NNODES / GN, 512, 0, stream>>>(x_all, WgT, bg, st, U, S0, x_all);

    // diff_conv #2 on xc
    spmm_kernel<<<NNODES, 128, 0, stream>>>(rowptr1, cols1, valsC1, S0, S0, S1, x_all, 72, 1.f, 0.f);
    spmm_kernel<<<NNODES, 128, 0, stream>>>(rowptr1, cols1, valsC1, S1, S0, (ushort*)nullptr, x_all, 144, 2.f, -1.f);
    spmm_kernel<<<NNODES, 128, 0, stream>>>(rowptr2, cols2, valsC2, S0, S0, S3, x_all, 216, 1.f, 0.f);
    spmm_kernel<<<NNODES, 128, 0, stream>>>(rowptr2, cols2, valsC2, S3, S0, (ushort*)nullptr, x_all, 288, 2.f, -1.f);

    // cand GEMM + tanh + GRU update + duplicated output
    cand_mfma<<<NNODES / GN, 256, 0, stream>>>(x_all, WcT, bc, st, U, out);
}